// Round 6
// baseline (32.315 us; speedup 1.0000x reference)
//
#include <hip/hip_runtime.h>
#include <math.h>

#define BLK  256
#define NPTS 4096
#define B    8
#define SP   8     // stage-2 split per (dir,b)
#define QPT  16

#define FOREACH_Q(OP) OP(0) OP(1) OP(2) OP(3) OP(4) OP(5) OP(6) OP(7) \
                      OP(8) OP(9) OP(10) OP(11) OP(12) OP(13) OP(14) OP(15)

// Stage 1: one block per (dir, batch, refchunk). 256 threads x 16 queries
// = 4096 queries/block (all queries of the (dir,b) pair).
// Refs split RS ways -> NPTS/RS refs in LDS as (x,y,z,||g||^2).
// Inner iter: 4 broadcast ds_read_b128 (prefetch for NEXT iter) +
// 16q x (12 fma + 2 min3) on the current 4 refs. pn deferred to stage 2.
template<int RS>
__global__ __launch_bounds__(BLK, 2) void chamfer_partial(
    const float* __restrict__ P,
    const float* __restrict__ G,
    float* __restrict__ partial)   // [2][B][RS][NPTS]
{
    constexpr int RCH = NPTS / RS;
    __shared__ float4 lds[RCH];

    const int dir = blockIdx.z;
    const int b   = blockIdx.y;
    const int r   = blockIdx.x;

    const float* __restrict__ Qb = (dir ? G : P) + (size_t)b * NPTS * 3;
    const float* __restrict__ Rb = (dir ? P : G) + (size_t)b * NPTS * 3;

    // stage this block's ref chunk
    const int j0 = r * RCH;
    for (int j = threadIdx.x; j < RCH; j += BLK) {
        float x = Rb[3 * (j0 + j) + 0];
        float y = Rb[3 * (j0 + j) + 1];
        float z = Rb[3 * (j0 + j) + 2];
        lds[j] = make_float4(x, y, z, fmaf(x, x, fmaf(y, y, z * z)));
    }

    // 16 queries in named scalars (overlaps with staging latency)
#define DECLQ(i) float m2x##i, m2y##i, m2z##i, acc##i;
    FOREACH_Q(DECLQ)
#undef DECLQ
#define LOADQ(i) { const int qi = (i) * BLK + threadIdx.x;                   \
        m2x##i = -2.f * Qb[3 * qi + 0];                                      \
        m2y##i = -2.f * Qb[3 * qi + 1];                                      \
        m2z##i = -2.f * Qb[3 * qi + 2];                                      \
        acc##i = 3.4e38f; }
    FOREACH_Q(LOADQ)
#undef LOADQ

    __syncthreads();

#define EVALQ(i) {                                                           \
        float t0 = fmaf(m2x##i, c0.x, c0.w);                                 \
        t0 = fmaf(m2y##i, c0.y, t0);                                         \
        t0 = fmaf(m2z##i, c0.z, t0);                                         \
        float t1 = fmaf(m2x##i, c1.x, c1.w);                                 \
        t1 = fmaf(m2y##i, c1.y, t1);                                         \
        t1 = fmaf(m2z##i, c1.z, t1);                                         \
        float t2 = fmaf(m2x##i, c2.x, c2.w);                                 \
        t2 = fmaf(m2y##i, c2.y, t2);                                         \
        t2 = fmaf(m2z##i, c2.z, t2);                                         \
        float t3 = fmaf(m2x##i, c3.x, c3.w);                                 \
        t3 = fmaf(m2y##i, c3.y, t3);                                         \
        t3 = fmaf(m2z##i, c3.z, t3);                                         \
        acc##i = fminf(fminf(t0, t1), fminf(fminf(t2, t3), acc##i)); }

    float4 c0 = lds[0], c1 = lds[1], c2 = lds[2], c3 = lds[3];
#pragma unroll 2
    for (int j = 0; j < RCH - 4; j += 4) {
        float4 n0 = lds[j + 4];      // prefetch next 4 refs
        float4 n1 = lds[j + 5];
        float4 n2 = lds[j + 6];
        float4 n3 = lds[j + 7];
        FOREACH_Q(EVALQ)
        c0 = n0; c1 = n1; c2 = n2; c3 = n3;
    }
    FOREACH_Q(EVALQ)                 // tail: last 4 refs
#undef EVALQ

    float* out_base = partial + (((size_t)dir * B + b) * RS + r) * NPTS;
#define STOREQ(i) out_base[(i) * BLK + threadIdx.x] = acc##i;
    FOREACH_Q(STOREQ)
#undef STOREQ
}

// Stage 2: grid = 2*B*SP blocks; min-combine RS partials per query,
// add pn, clamp, block-sum.
template<int RS>
__global__ __launch_bounds__(BLK) void chamfer_reduce(
    const float* __restrict__ P, const float* __restrict__ G,
    const float* __restrict__ partial, float* __restrict__ sums)
{
    const int dirb = blockIdx.x / SP;
    const int sp   = blockIdx.x % SP;
    const int dir  = dirb >> 3;
    const int b    = dirb & 7;
    const float* __restrict__ Qb   = (dir ? G : P) + (size_t)b * NPTS * 3;
    const float* __restrict__ base = partial + (size_t)dirb * RS * NPTS;

    float sum = 0.f;
#pragma unroll
    for (int i = 0; i < NPTS / SP / BLK; ++i) {
        const int q = sp * (NPTS / SP) + i * BLK + threadIdx.x;
        float mn = base[q];
#pragma unroll
        for (int rr = 1; rr < RS; ++rr) mn = fminf(mn, base[(size_t)rr * NPTS + q]);
        const float x = Qb[3 * q + 0];
        const float y = Qb[3 * q + 1];
        const float z = Qb[3 * q + 2];
        sum += fmaxf(fmaf(x, x, fmaf(y, y, z * z)) + mn, 0.f);
    }

    __shared__ float red[BLK];
    red[threadIdx.x] = sum;
    __syncthreads();
    if (threadIdx.x < 128) red[threadIdx.x] += red[threadIdx.x + 128];
    __syncthreads();
    if (threadIdx.x < 64) {
        float v = red[threadIdx.x] + red[threadIdx.x + 64];
#pragma unroll
        for (int off = 32; off > 0; off >>= 1) v += __shfl_down(v, off, 64);
        if (threadIdx.x == 0) sums[blockIdx.x] = v;   // [dirb][sp]
    }
}

// Stage 3: 16 x sqrt(mean), then the 3 scalar outputs.
__global__ __launch_bounds__(64) void chamfer_final(
    const float* __restrict__ sums, float* __restrict__ out)
{
    __shared__ float r16[16];
    if (threadIdx.x < 16) {
        float s = 0.f;
#pragma unroll
        for (int sp = 0; sp < SP; ++sp) s += sums[threadIdx.x * SP + sp];
        r16[threadIdx.x] = sqrtf(s / (float)NPTS);
    }
    __syncthreads();
    if (threadIdx.x == 0) {
        float p2g = 0.f, g2p = 0.f;
#pragma unroll
        for (int bb = 0; bb < B; ++bb) { p2g += r16[bb]; g2p += r16[B + bb]; }
        p2g *= (1.0f / B);
        g2p *= (1.0f / B);
        out[0] = 0.5f * (p2g + g2p);
        out[1] = p2g;
        out[2] = g2p;
    }
}

extern "C" void kernel_launch(void* const* d_in, const int* in_sizes, int n_in,
                              void* d_out, int out_size, void* d_ws, size_t ws_size,
                              hipStream_t stream) {
    const float* points = (const float*)d_in[0];
    const float* gts    = (const float*)d_in[1];
    float* out = (float*)d_out;
    float* partial = (float*)d_ws;

    const size_t need32 = (size_t)2 * B * 32 * NPTS * 4 + 1024;
    const bool use32 = (ws_size >= need32);

    if (use32) {
        float* sums = partial + (size_t)2 * B * 32 * NPTS;
        dim3 grid1(32, B, 2);       // 512 blocks -> 2 blocks/CU
        chamfer_partial<32><<<grid1, BLK, 0, stream>>>(points, gts, partial);
        chamfer_reduce<32><<<dim3(2 * B * SP), BLK, 0, stream>>>(points, gts, partial, sums);
        chamfer_final<<<dim3(1), 64, 0, stream>>>(sums, out);
    } else {
        float* sums = partial + (size_t)2 * B * 16 * NPTS;
        dim3 grid1(16, B, 2);       // 256 blocks
        chamfer_partial<16><<<grid1, BLK, 0, stream>>>(points, gts, partial);
        chamfer_reduce<16><<<dim3(2 * B * SP), BLK, 0, stream>>>(points, gts, partial, sums);
        chamfer_final<<<dim3(1), 64, 0, stream>>>(sums, out);
    }
}